// Round 4
// baseline (1629.498 us; speedup 1.0000x reference)
//
#include <hip/hip_runtime.h>
#include <stdint.h>

// Word2MatEncoder: out[b] = prod_{s=0..63} table[sent[b,s]]  (28x28 fp32 chain)
//
// R9: R7/R8 post-mortems: any restructuring outside the R5 macro skeleton
// (named ping-pong arrays, LDS-staged B, global_load_lds) generated huge
// compiler scratch/overfetch traffic (R7: 15.5GB, R8 combine4: 458MB vs 32MB
// logical). So: keep the R5 kernel BYTE-IDENTICAL in its matmul/DMA/address
// code and fix only the pipeline, which R0's profile shows is the bottleneck
// (step ~5.6k cyc vs ~1.6k cyc FMA issue; VALUBusy 31%): R5 issues the next
// matrix's DMA and then immediately waits vmcnt(0) on it -- full DMA drain
// exposed every step.
// Change (minimal, schedule-only):
//  - lds[2][BUF_F] double buffer (56KB -> 2 blocks/CU). Prologue stages
//    mats 1 and 2; step s computes mat s from buf[cur] while mat s+1 flies.
//  - steady-state wait is vmcnt(28): only the 28 newest loads (next buffer)
//    stay outstanding across the matmul (counted-vmcnt, m218 pattern).
//    Peeled final step waits vmcnt(0). Order-robust: at 63 outstanding
//    (7 A0 + 56 DMA) vmcnt(28) retires the oldest 35 >= A0+buf0.
//  - NO __syncthreads (its lowering drains vmcnt(0) and would kill the
//    pipeline). Blocks are single-wave; LDS coherence needs only:
//    lgkmcnt(0)+sched_barrier(0) after matmul before overwriting the
//    consumed buffer (rule #18), vmcnt(N)+sched_barrier(0) at step top.
// Same (16,4) segmentation, same k-ascending fmaf chains -> identical
// numerics. fp32 throughout (no fp32 MFMA on CDNA4).

#define D 28
#define EMB 784
#define SEQ 64
#define NITEMS 2048
#define LPI 7            // lanes per task
#define IPW 9            // tasks per wave (63 of 64 lanes active)
#define RPL 4            // rows of the running product per lane
#define NCHUNK 28        // DMA chunks per matrix-set (1 row x 9 slots each)
#define CHUNK_F 256      // floats per chunk (64 lanes x 16B)
#define BUF_F (NCHUNK * CHUNK_F)  // 7168 floats = 28672 B per buffer

typedef __attribute__((address_space(3))) uint32_t lds_u32;
typedef const __attribute__((address_space(1))) uint32_t glb_u32;

// Stage one matrix per slot into LDS buffer at lds0. glane = matrix base +
// rl*16B (per lane); chunk t pulls row t of each slot's matrix.
__device__ __forceinline__ void dma_mat(const float* glane, float* lds0) {
#pragma unroll
  for (int t = 0; t < NCHUNK; ++t)
    __builtin_amdgcn_global_load_lds((glb_u32*)(glane + t * D),
                                     (lds_u32*)(lds0 + t * CHUNK_F), 16, 0, 0);
}

// Cc = Aa @ M   (M staged at Bs with the chunk layout above) -- verbatim R5.
#define MATMUL(Aa, Cc)                                                         \
  do {                                                                         \
    _Pragma("unroll") for (int k = 0; k < D; ++k) {                            \
      _Pragma("unroll") for (int jv = 0; jv < 7; ++jv) {                       \
        float4 m = *(const float4*)(Bs + k * CHUNK_F + 4 * jv);                \
        _Pragma("unroll") for (int r = 0; r < RPL; ++r) {                      \
          float a = Aa[r][k];                                                  \
          if (k == 0) {                                                        \
            Cc[r][4 * jv + 0] = a * m.x;                                       \
            Cc[r][4 * jv + 1] = a * m.y;                                       \
            Cc[r][4 * jv + 2] = a * m.z;                                       \
            Cc[r][4 * jv + 3] = a * m.w;                                       \
          } else {                                                             \
            Cc[r][4 * jv + 0] = fmaf(a, m.x, Cc[r][4 * jv + 0]);               \
            Cc[r][4 * jv + 1] = fmaf(a, m.y, Cc[r][4 * jv + 1]);               \
            Cc[r][4 * jv + 2] = fmaf(a, m.z, Cc[r][4 * jv + 2]);               \
            Cc[r][4 * jv + 3] = fmaf(a, m.w, Cc[r][4 * jv + 3]);               \
          }                                                                    \
        }                                                                      \
      }                                                                        \
    }                                                                          \
  } while (0)

// Steady-state step: mat s guaranteed landed by vmcnt(28) (mat s+1 keeps
// flying). After compute, drain this buffer's ds_reads, then restage it with
// mat s+2 and prefetch the s+3 pointer.
#define STEP(Aa, Cc)                                                           \
  do {                                                                         \
    asm volatile("s_waitcnt vmcnt(28)" ::: "memory");                          \
    __builtin_amdgcn_sched_barrier(0);                                         \
    const float* Bs = &lds[cur][0] + slot * (LPI * 4);                         \
    MATMUL(Aa, Cc);                                                            \
    asm volatile("s_waitcnt lgkmcnt(0)" ::: "memory");                         \
    __builtin_amdgcn_sched_barrier(0);                                         \
    if (s + 2 < SEG_LEN) {                                                     \
      dma_mat(gn, &lds[cur][0]);                                               \
      int nn = (s + 3 < SEG_LEN) ? s + 3 : SEG_LEN - 1;                        \
      gn = glane(nn);                                                          \
    }                                                                          \
    cur ^= 1;                                                                  \
    ++s;                                                                       \
  } while (0)

#define STEP_LAST(Aa, Cc)                                                      \
  do {                                                                         \
    asm volatile("s_waitcnt vmcnt(0)" ::: "memory");                           \
    __builtin_amdgcn_sched_barrier(0);                                         \
    const float* Bs = &lds[cur][0] + slot * (LPI * 4);                         \
    MATMUL(Aa, Cc);                                                            \
  } while (0)

// Product of SEG_LEN consecutive matrices (SEG_LEN >= 4, even; result in A1).
// GATHER: matrices are table[sp[s]]; else dense at src + (task*SEG_LEN+s)*EMB.
template <int SEG_LEN, int PSEG, bool GATHER>
__global__ __launch_bounds__(64, 1) void chain_kernel(
    const float* __restrict__ src, const int* __restrict__ sent,
    float* __restrict__ dst, int ntask) {
  __shared__ __align__(16) float lds[2][BUF_F];

  const int lane = threadIdx.x;
  int slot = lane / LPI;
  int rl = lane - slot * LPI;
  if (slot >= IPW) { slot = IPW - 1; rl = LPI - 1; }  // lane 63 mirrors lane 62
  int task = blockIdx.x * IPW + slot;
  if (task >= ntask) task = ntask - 1;  // tail duplicates (same values, benign)

  const int* sp = nullptr;
  if (GATHER) {
    const int item = task / PSEG;
    const int seg = task - item * PSEG;
    sp = sent + item * SEQ + seg * SEG_LEN;
  }
  auto glane = [&](int s) -> const float* {
    const float* m = GATHER ? src + (size_t)sp[s] * EMB
                            : src + ((size_t)task * SEG_LEN + s) * EMB;
    return m + rl * 4;  // this lane's 16B slice of each row
  };

  float A0[RPL][D], A1[RPL][D];

  // A0 = this lane's rows (rl*4 .. rl*4+3) of the first matrix (direct loads)
  {
    const float* m0 = GATHER ? src + (size_t)sp[0] * EMB
                             : src + (size_t)task * SEG_LEN * EMB;
#pragma unroll
    for (int r = 0; r < RPL; ++r) {
      const float* rp = m0 + (rl * RPL + r) * D;
#pragma unroll
      for (int jv = 0; jv < 7; ++jv) {
        float4 v = *(const float4*)(rp + 4 * jv);
        A0[r][4 * jv + 0] = v.x;
        A0[r][4 * jv + 1] = v.y;
        A0[r][4 * jv + 2] = v.z;
        A0[r][4 * jv + 3] = v.w;
      }
    }
  }

  // stage matrices 1 and 2 into the two buffers; prefetch pointer for mat 3
  dma_mat(glane(1), &lds[0][0]);
  dma_mat(glane(2), &lds[1][0]);
  const float* gn = glane(3 < SEG_LEN ? 3 : SEG_LEN - 1);

  int s = 1, cur = 0;
#pragma unroll 1
  for (int p = 0; p < (SEG_LEN - 2) / 2; ++p) {
    STEP(A0, A1);
    STEP(A1, A0);
  }
  STEP_LAST(A0, A1);  // final step (SEG_LEN-1 odd) -> result in A1

  // store
  {
    float* op = dst + (size_t)task * EMB;
#pragma unroll
    for (int r = 0; r < RPL; ++r) {
      float* rp = op + (rl * RPL + r) * D;
#pragma unroll
      for (int jv = 0; jv < 7; ++jv) {
        *(float4*)(rp + 4 * jv) =
            make_float4(A1[r][4 * jv + 0], A1[r][4 * jv + 1],
                        A1[r][4 * jv + 2], A1[r][4 * jv + 3]);
      }
    }
  }
}

extern "C" void kernel_launch(void* const* d_in, const int* in_sizes, int n_in,
                              void* d_out, int out_size, void* d_ws,
                              size_t ws_size, hipStream_t stream) {
  const float* table = (const float*)d_in[0];
  const int* sent = (const int*)d_in[1];
  float* out = (float*)d_out;

  const size_t need = (size_t)NITEMS * 4 * EMB * sizeof(float);  // 25.7 MB
  if (ws_size >= need) {
    float* pbuf = (float*)d_ws;
    // phase 1: 4 segments of 16 per item -> 8192 partials (contiguous per item)
    const int ntask1 = NITEMS * 4;
    chain_kernel<16, 4, true><<<(ntask1 + IPW - 1) / IPW, 64, 0, stream>>>(
        table, sent, pbuf, ntask1);
    // phase 2: chain each item's 4 partials -> d_out (same machinery)
    chain_kernel<4, 1, false><<<(NITEMS + IPW - 1) / IPW, 64, 0, stream>>>(
        pbuf, nullptr, out, NITEMS);
  } else {
    // fallback: direct 64-long chain per item straight into d_out
    chain_kernel<64, 1, true><<<(NITEMS + IPW - 1) / IPW, 64, 0, stream>>>(
        table, sent, out, NITEMS);
  }
}

// Round 5
// 241.894 us; speedup vs baseline: 6.7364x; 6.7364x over previous
//
#include <hip/hip_runtime.h>
#include <stdint.h>

// Word2MatEncoder: out[b] = prod_{s=0..63} table[sent[b,s]]  (28x28 fp32 chain)
//
// R10: R7/R8/R9 all poisoned codegen (scratch explosions: 15.5GB / 458MB /
// 3.2GB extra HBM traffic, VGPR 256) whenever the R5 sync/buffer machinery
// (asm waitcnt fences, double-buffer, counted vmcnt) was touched. Conclusion:
// keep the R5 chain skeleton VERBATIM (__syncthreads, single 28KB buffer,
// global_load_lds staging, named ping-pong arrays, 144 VGPR proven).
// R0's profile: phase 1 = 124us, phase 2 = ~120us for ~5% of the work (3
// matmul steps, 228 blocks) -- a nearly-fixed cost per dispatch. So this
// round ELIMINATES phase 2 instead of pipelining phase 1:
//  - one block = 2 items x 4 segments (slots 0..7; slot 8 lanes mirror
//    slot 7 -- identical addresses/values, benign). Grid 8192/8 = 1024.
//  - chain part: verbatim R5, SEG_LEN=16, PSEG=4 gather (slot s -> item
//    task/4, segment task%4).
//  - fused combine epilogue (same sequential association ((P0*P1)*P2)*P3 as
//    the passing 2-phase version): slots 1,2,3 (cols 0,28,56) and 5,6,7
//    (cols 84,112,140) ds_write their segment products (A1) into LDS in the
//    exact k*256+col+4jv layout MATMUL reads; one __syncthreads; slots 0/4
//    run 3 MATMUL rounds with Bs = cbase + round*28; result lands in A0;
//    only slots 0/4 store. No new register arrays, no asm, no workspace.
// fp32 throughout (no fp32 MFMA on CDNA4; bf16 error compounds over 63 muls).

#define D 28
#define EMB 784
#define SEQ 64
#define NITEMS 2048
#define LPI 7            // lanes per slot
#define SPW 8            // useful slots per wave (2 items x 4 segments)
#define RPL 4            // rows of the running product per lane
#define NCHUNK 28        // DMA chunks per matrix-set (1 row x 9 slot-lanes)
#define CHUNK_F 256      // floats per chunk (64 lanes x 16B)
#define BUF_F (NCHUNK * CHUNK_F)  // 7168 floats = 28672 B

typedef __attribute__((address_space(3))) uint32_t lds_u32;
typedef const __attribute__((address_space(1))) uint32_t glb_u32;

// Stage one matrix per slot into LDS. glane = matrix base + rl*16B (per lane);
// chunk t pulls row t (bytes [t*112, t*112+16) per lane) of each slot's matrix.
__device__ __forceinline__ void dma_mat(const float* glane, float* lds0) {
#pragma unroll
  for (int t = 0; t < NCHUNK; ++t)
    __builtin_amdgcn_global_load_lds((glb_u32*)(glane + t * D),
                                     (lds_u32*)(lds0 + t * CHUNK_F), 16, 0, 0);
}

// Cc = Aa @ M   (M staged in LDS at Bs with the chunk layout above) -- R5.
#define MATMUL(Aa, Cc)                                                         \
  do {                                                                         \
    _Pragma("unroll") for (int k = 0; k < D; ++k) {                            \
      _Pragma("unroll") for (int jv = 0; jv < 7; ++jv) {                       \
        float4 m = *(const float4*)(Bs + k * CHUNK_F + 4 * jv);                \
        _Pragma("unroll") for (int r = 0; r < RPL; ++r) {                      \
          float a = Aa[r][k];                                                  \
          if (k == 0) {                                                        \
            Cc[r][4 * jv + 0] = a * m.x;                                       \
            Cc[r][4 * jv + 1] = a * m.y;                                       \
            Cc[r][4 * jv + 2] = a * m.z;                                       \
            Cc[r][4 * jv + 3] = a * m.w;                                       \
          } else {                                                             \
            Cc[r][4 * jv + 0] = fmaf(a, m.x, Cc[r][4 * jv + 0]);               \
            Cc[r][4 * jv + 1] = fmaf(a, m.y, Cc[r][4 * jv + 1]);               \
            Cc[r][4 * jv + 2] = fmaf(a, m.z, Cc[r][4 * jv + 2]);               \
            Cc[r][4 * jv + 3] = fmaf(a, m.w, Cc[r][4 * jv + 3]);               \
          }                                                                    \
        }                                                                      \
      }                                                                        \
    }                                                                          \
  } while (0)

// One chain step: wait staged matrix, multiply, then DMA the next one. -- R5.
#define STEP(Aa, Cc)                                                           \
  do {                                                                         \
    __builtin_amdgcn_s_waitcnt(0x0f70); /* vmcnt(0): matrix landed */          \
    __syncthreads();                                                           \
    MATMUL(Aa, Cc);                                                            \
    __syncthreads(); /* all LDS reads drained before overwrite */              \
    if (s + 1 < SEG_LEN) {                                                     \
      dma_mat(gn, lds);                                                        \
      int nn = (s + 2 < SEG_LEN) ? s + 2 : SEG_LEN - 1;                        \
      gn = glane(nn);                                                          \
    }                                                                          \
    ++s;                                                                       \
  } while (0)

// Fused: chain 16 matrices per slot, then combine each item's 4 segment
// products in-block. Writes final item products straight to dst.
__global__ __launch_bounds__(64, 1) void fused_kernel(
    const float* __restrict__ src, const int* __restrict__ sent,
    float* __restrict__ dst, int ntask) {
  constexpr int SEG_LEN = 16;
  constexpr int PSEG = 4;
  __shared__ __align__(16) float lds[BUF_F];

  const int lane = threadIdx.x;
  int slot = lane / LPI;
  int rl = lane - slot * LPI;
  if (slot >= SPW) {  // lanes 56..63 mirror slot 7 (rl 0..6, lane63 -> 6)
    slot = SPW - 1;
    rl = (lane - 56 < LPI) ? lane - 56 : LPI - 1;
  }
  int task = blockIdx.x * SPW + slot;
  if (task >= ntask) task = ntask - 1;  // safety (8192 % 8 == 0: no tail)

  const int item = task / PSEG;
  const int seg = task - item * PSEG;
  const int* sp = sent + item * SEQ + seg * SEG_LEN;

  auto glane = [&](int s) -> const float* {
    return src + (size_t)sp[s] * EMB + rl * 4;  // this lane's 16B row slice
  };

  float A0[RPL][D], A1[RPL][D];

  // A0 = this lane's rows (rl*4 .. rl*4+3) of the first matrix (direct loads)
  {
    const float* m0 = src + (size_t)sp[0] * EMB;
#pragma unroll
    for (int r = 0; r < RPL; ++r) {
      const float* rp = m0 + (rl * RPL + r) * D;
#pragma unroll
      for (int jv = 0; jv < 7; ++jv) {
        float4 v = *(const float4*)(rp + 4 * jv);
        A0[r][4 * jv + 0] = v.x;
        A0[r][4 * jv + 1] = v.y;
        A0[r][4 * jv + 2] = v.z;
        A0[r][4 * jv + 3] = v.w;
      }
    }
  }

  // stage matrix 1; prefetch pointer for matrix 2
  dma_mat(glane(1), lds);
  const float* gn = glane(2);
  const float* Bs = lds + slot * (LPI * 4);  // slot*28 floats

  int s = 1;
#pragma unroll 1
  for (int p = 0; p < (SEG_LEN - 1) / 2; ++p) {
    STEP(A0, A1);
    STEP(A1, A0);
  }
  STEP(A0, A1);  // 15th step -> segment product in A1

  // ---- fused combine: out[item] = ((P0@P1)@P2)@P3 ----
  __syncthreads();  // chain's last LDS reads drained before overwrite

  // writers: slots 1,2,3 -> cols 0,28,56 ; slots 5,6,7 -> cols 84,112,140.
  // layout matches MATMUL's read: element [k][j] at lds[k*256 + col + j].
  {
    const int wslot = (slot >= 4) ? slot - 4 : slot;  // 0..3 within item
    if (wslot != 0) {
      const int col = ((slot >= 4) ? 3 : 0) * D + (wslot - 1) * D;
      float* wp = lds + col;
#pragma unroll
      for (int r = 0; r < RPL; ++r) {
        const int k = rl * RPL + r;
#pragma unroll
        for (int jv = 0; jv < 7; ++jv) {
          *(float4*)(wp + k * CHUNK_F + 4 * jv) =
              make_float4(A1[r][4 * jv + 0], A1[r][4 * jv + 1],
                          A1[r][4 * jv + 2], A1[r][4 * jv + 3]);
        }
      }
    }
  }
  __syncthreads();  // partials visible to readers

  // readers: slots 0 and 4 chain through their item's 3 partials.
  // (all slots execute; non-readers compute garbage into dead arrays)
  const int cbase = (slot >= 4) ? 3 * D : 0;
  {
    const float* Bs = lds + cbase + 0 * D;  // P1
    MATMUL(A1, A0);                         // A0 = P0 @ P1
  }
  {
    const float* Bs = lds + cbase + 1 * D;  // P2
    MATMUL(A0, A1);                         // A1 = (P0@P1) @ P2
  }
  {
    const float* Bs = lds + cbase + 2 * D;  // P3
    MATMUL(A1, A0);                         // A0 = ((P0@P1)@P2) @ P3
  }

  // store: only the reader slots (0 and 4) hold a finished item product.
  if (slot == 0 || slot == 4) {
    float* op = dst + (size_t)item * EMB;
#pragma unroll
    for (int r = 0; r < RPL; ++r) {
      float* rp = op + (rl * RPL + r) * D;
#pragma unroll
      for (int jv = 0; jv < 7; ++jv) {
        *(float4*)(rp + 4 * jv) =
            make_float4(A0[r][4 * jv + 0], A0[r][4 * jv + 1],
                        A0[r][4 * jv + 2], A0[r][4 * jv + 3]);
      }
    }
  }
}

extern "C" void kernel_launch(void* const* d_in, const int* in_sizes, int n_in,
                              void* d_out, int out_size, void* d_ws,
                              size_t ws_size, hipStream_t stream) {
  const float* table = (const float*)d_in[0];
  const int* sent = (const int*)d_in[1];
  float* out = (float*)d_out;

  // single fused dispatch: 8192 segment-tasks, 8 per block -> 1024 blocks
  const int ntask = NITEMS * 4;
  fused_kernel<<<ntask / SPW, 64, 0, stream>>>(table, sent, out, ntask);
}